// Round 14
// baseline (183.743 us; speedup 1.0000x reference)
//
#include <hip/hip_runtime.h>

#define BB 4
#define TT 2048
#define CC 1024
#define HH 16
#define DD 64

typedef unsigned short u16;
typedef unsigned int u32;
typedef __bf16 bf16;
typedef __attribute__((ext_vector_type(8))) bf16 bf16x8;
typedef __attribute__((ext_vector_type(8))) u16 u16x8;
typedef __attribute__((ext_vector_type(4))) u16 u16x4;
typedef __attribute__((ext_vector_type(4))) float f32x4;

static __device__ __forceinline__ u16 f2b(float f) {
  unsigned u = __builtin_bit_cast(unsigned, f);
  u += 0x7fffu + ((u >> 16) & 1u);
  return (u16)(u >> 16);
}
static __device__ __forceinline__ u16 bfc(float f) {
  return __builtin_bit_cast(u16, (__bf16)f);
}
static __device__ __forceinline__ float max3f(float a, float b, float c) {
  float d;
  asm("v_max3_f32 %0, %1, %2, %3" : "=v"(d) : "v"(a), "v"(b), "v"(c));
  return d;
}

// ---- fused prep: [0,4096) cvt x->bf16 | [4096,8192) transpose W | [8192,8196) mask ----
__global__ __launch_bounds__(256) void prep_kernel(
    const float* __restrict__ x, const int* __restrict__ am,
    const float* __restrict__ w0, const float* __restrict__ w1,
    const float* __restrict__ w2, const float* __restrict__ w3,
    u16* __restrict__ xb, u16* __restrict__ wqkvT, u16* __restrict__ wpT,
    float* __restrict__ gm, u32* __restrict__ fwords) {
  __shared__ float t[32][33];
  const int bid = blockIdx.x, tid = threadIdx.x;
  if (bid < 4096) {
    int i = bid * 256 + tid;
    const float4* p4 = reinterpret_cast<const float4*>(x) + (size_t)i * 2;
    float4 a = p4[0], b = p4[1];
    u16x8 o;
    o[0] = f2b(a.x); o[1] = f2b(a.y); o[2] = f2b(a.z); o[3] = f2b(a.w);
    o[4] = f2b(b.x); o[5] = f2b(b.y); o[6] = f2b(b.z); o[7] = f2b(b.w);
    *reinterpret_cast<u16x8*>(xb + (size_t)i * 8) = o;
  } else if (bid < 8192) {
    int r2 = bid - 4096;
    int z = r2 >> 10, rem = r2 & 1023;
    int k0 = (rem & 31) * 32, n0 = (rem >> 5) * 32;
    const float* src = z == 0 ? w0 : z == 1 ? w1 : z == 2 ? w2 : w3;
    u16* dst = z < 3 ? wqkvT + (size_t)z * CC * CC : wpT;
    int tx = tid & 31, ty = tid >> 5;
#pragma unroll
    for (int i = 0; i < 4; ++i)
      t[ty + i * 8][tx] = src[(size_t)(k0 + ty + i * 8) * CC + n0 + tx];
    __syncthreads();
#pragma unroll
    for (int i = 0; i < 4; ++i)
      dst[(size_t)(n0 + ty + i * 8) * CC + k0 + tx] = f2b(t[tx][ty + i * 8]);
  } else {
    __shared__ u32 sf[32];
    int b = bid - 8192;
    int lane = tid & 63, w = tid >> 6;
#pragma unroll
    for (int j = 0; j < 8; ++j) {
      int c = w * 8 + j;
      int i = c * 64 + lane;
      int v = am[b * TT + i];
      gm[b * TT + i] = v ? 0.f : -1e30f;
      unsigned long long bal = __ballot(v != 0);
      if (lane == 0) sf[c] = (bal == ~0ull) ? 1u : 0u;
    }
    __syncthreads();
    if (tid == 0) {
      u32 fw = 0;
      for (int c = 0; c < 32; ++c) fw |= sf[c] << c;
      fwords[b] = fw;
    }
  }
}

// ------- QKV GEMM: 128x128, BK=64, dbuf swizzled LDS + counted vmcnt + XCD swizzle -------
__global__ __launch_bounds__(256) void qkv_gemm_kernel(
    const u16* __restrict__ A, const u16* __restrict__ Bt,
    const float* __restrict__ bq, const float* __restrict__ bk, const float* __restrict__ bv,
    u16* __restrict__ q_out, u16* __restrict__ k_out, u16* __restrict__ v_out) {
  __shared__ __align__(16) char LDS[65536];  // A[2][128*64] | B[2][128*64] bf16
  const int tid = threadIdx.x, lane = tid & 63, w = tid >> 6;
  const int wm = w >> 1, wn = w & 1;
  const int lq = lane & 15, g = lane >> 4;
  // XCD-chunked bijective swizzle: nwg = 1536, chunk = 192 per XCD -> each XCD keeps
  // 3 B-panels (768 KB) L2-resident, reused across 64 m-blocks.
  const int flat = blockIdx.y * 64 + blockIdx.x;
  const int swz = (flat & 7) * 192 + (flat >> 3);
  const int m0 = (swz & 63) * 128, n0 = (swz >> 6) * 128;
  const int l3 = lane >> 3;
  const int swb = ((lane & 7) ^ (l3 & 7)) * 16;
  f32x4 acc[4][4] = {};

  auto STAGE = [&](int db, int kt) {
    const int ko = kt * 128;
#pragma unroll
    for (int r = 0; r < 4; ++r) {
      int rb = r * 32 + w * 8;
      __builtin_amdgcn_global_load_lds(
          (const __attribute__((address_space(1))) void*)(
              (const char*)A + (size_t)(m0 + rb + l3) * 2048 + ko + swb),
          (__attribute__((address_space(3))) void*)(LDS + db * 16384 + rb * 128), 16, 0, 0);
      __builtin_amdgcn_global_load_lds(
          (const __attribute__((address_space(1))) void*)(
              (const char*)Bt + (size_t)(n0 + rb + l3) * 2048 + ko + swb),
          (__attribute__((address_space(3))) void*)(LDS + 32768 + db * 16384 + rb * 128), 16, 0, 0);
    }
  };

  const int acol0 = (g * 16) ^ ((lq & 7) << 4);
  const int acol1 = (64 + g * 16) ^ ((lq & 7) << 4);
  const int aBase = wm * 8192 + lq * 128;
  const int bBase = 32768 + wn * 8192 + lq * 128;

  STAGE(0, 0);
  STAGE(1, 1);
  for (int kt = 0; kt < 16; ++kt) {
    if (kt == 15) asm volatile("s_waitcnt vmcnt(0)" ::: "memory");
    else          asm volatile("s_waitcnt vmcnt(8)" ::: "memory");
    asm volatile("s_barrier" ::: "memory");
    const int db = kt & 1;
    const char* la = LDS + db * 16384 + aBase;
    const char* lb = LDS + db * 16384 + bBase;
    bf16x8 af[4][2], bfr[4][2];
#pragma unroll
    for (int i = 0; i < 4; ++i) {
      af[i][0] = *reinterpret_cast<const bf16x8*>(la + i * 2048 + acol0);
      af[i][1] = *reinterpret_cast<const bf16x8*>(la + i * 2048 + acol1);
      bfr[i][0] = *reinterpret_cast<const bf16x8*>(lb + i * 2048 + acol0);
      bfr[i][1] = *reinterpret_cast<const bf16x8*>(lb + i * 2048 + acol1);
    }
    asm volatile("s_waitcnt lgkmcnt(0)" ::: "memory");
    __builtin_amdgcn_sched_barrier(0);
    __builtin_amdgcn_s_setprio(1);
#pragma unroll
    for (int i = 0; i < 4; ++i)
#pragma unroll
      for (int j = 0; j < 4; ++j) {
        acc[i][j] = __builtin_amdgcn_mfma_f32_16x16x32_bf16(af[i][0], bfr[j][0], acc[i][j], 0, 0, 0);
        acc[i][j] = __builtin_amdgcn_mfma_f32_16x16x32_bf16(af[i][1], bfr[j][1], acc[i][j], 0, 0, 0);
      }
    __builtin_amdgcn_s_setprio(0);
    asm volatile("s_barrier" ::: "memory");
    if (kt + 2 < 16) STAGE(db, kt + 2);
  }

  // epilogue: scatter
  const int g3 = n0 >> 10;  // 0:Q 1:K 2:V (uniform per block)
  const int mrow = m0 + wm * 64;
  const int ncol = n0 + wn * 64;
  if (g3 < 2) {
    u16* dst = g3 == 0 ? q_out : k_out;
    const float* bias = g3 == 0 ? bq : bk;
    const float scl = g3 == 0 ? 0.18033688f : 1.0f;  // Q pre-scale: 0.125*log2(e)
#pragma unroll
    for (int i = 0; i < 4; ++i)
#pragma unroll
      for (int j = 0; j < 4; ++j) {
        int n = ncol + j * 16 + lq;
        int h = (n >> 6) & 15, d = n & 63;
        float bb = bias[n & 1023];
#pragma unroll
        for (int r = 0; r < 4; ++r) {
          int m = mrow + i * 16 + g * 4 + r;
          int b = m >> 11, t = m & 2047;
          dst[(((size_t)(b * HH + h)) * TT + t) * DD + d] = f2b((acc[i][j][r] + bb) * scl);
        }
      }
  } else {
#pragma unroll
    for (int i = 0; i < 4; ++i)
#pragma unroll
      for (int j = 0; j < 4; ++j) {
        int n = ncol + j * 16 + lq;
        int h = (n >> 6) & 15, d = n & 63;
        float bb = bv[n & 1023];
        int mb = mrow + i * 16 + g * 4;
        int b = mb >> 11, t = mb & 2047;
        u16x4 vv;
#pragma unroll
        for (int r = 0; r < 4; ++r) vv[r] = f2b(acc[i][j][r] + bb);
        *reinterpret_cast<u16x4*>(v_out + (((size_t)(b * HH + h)) * DD + d) * TT + t) = vv;
      }
  }
}

// -------- proj GEMM: 128x128, BK=64, dbuf swizzled LDS + counted vmcnt + XCD swizzle --------
__global__ __launch_bounds__(256) void proj_gemm_kernel(
    const u16* __restrict__ A, const u16* __restrict__ Bt,
    const float* __restrict__ bias, float* __restrict__ f_out) {
  __shared__ __align__(16) char LDS[65536];
  const int tid = threadIdx.x, lane = tid & 63, w = tid >> 6;
  const int wm = w >> 1, wn = w & 1;
  const int lq = lane & 15, g = lane >> 4;
  // XCD-chunked swizzle: nwg = 512, chunk = 64 -> 1 B-panel per XCD, reused 64x.
  const int flat = blockIdx.y * 64 + blockIdx.x;
  const int swz = (flat & 7) * 64 + (flat >> 3);
  const int m0 = (swz & 63) * 128, n0 = (swz >> 6) * 128;
  const int l3 = lane >> 3;
  const int swb = ((lane & 7) ^ (l3 & 7)) * 16;
  f32x4 acc[4][4] = {};

  auto STAGE = [&](int db, int kt) {
    const int ko = kt * 128;
#pragma unroll
    for (int r = 0; r < 4; ++r) {
      int rb = r * 32 + w * 8;
      __builtin_amdgcn_global_load_lds(
          (const __attribute__((address_space(1))) void*)(
              (const char*)A + (size_t)(m0 + rb + l3) * 2048 + ko + swb),
          (__attribute__((address_space(3))) void*)(LDS + db * 16384 + rb * 128), 16, 0, 0);
      __builtin_amdgcn_global_load_lds(
          (const __attribute__((address_space(1))) void*)(
              (const char*)Bt + (size_t)(n0 + rb + l3) * 2048 + ko + swb),
          (__attribute__((address_space(3))) void*)(LDS + 32768 + db * 16384 + rb * 128), 16, 0, 0);
    }
  };

  const int acol0 = (g * 16) ^ ((lq & 7) << 4);
  const int acol1 = (64 + g * 16) ^ ((lq & 7) << 4);
  const int aBase = wm * 8192 + lq * 128;
  const int bBase = 32768 + wn * 8192 + lq * 128;

  STAGE(0, 0);
  STAGE(1, 1);
  for (int kt = 0; kt < 16; ++kt) {
    if (kt == 15) asm volatile("s_waitcnt vmcnt(0)" ::: "memory");
    else          asm volatile("s_waitcnt vmcnt(8)" ::: "memory");
    asm volatile("s_barrier" ::: "memory");
    const int db = kt & 1;
    const char* la = LDS + db * 16384 + aBase;
    const char* lb = LDS + db * 16384 + bBase;
    bf16x8 af[4][2], bfr[4][2];
#pragma unroll
    for (int i = 0; i < 4; ++i) {
      af[i][0] = *reinterpret_cast<const bf16x8*>(la + i * 2048 + acol0);
      af[i][1] = *reinterpret_cast<const bf16x8*>(la + i * 2048 + acol1);
      bfr[i][0] = *reinterpret_cast<const bf16x8*>(lb + i * 2048 + acol0);
      bfr[i][1] = *reinterpret_cast<const bf16x8*>(lb + i * 2048 + acol1);
    }
    asm volatile("s_waitcnt lgkmcnt(0)" ::: "memory");
    __builtin_amdgcn_sched_barrier(0);
    __builtin_amdgcn_s_setprio(1);
#pragma unroll
    for (int i = 0; i < 4; ++i)
#pragma unroll
      for (int j = 0; j < 4; ++j) {
        acc[i][j] = __builtin_amdgcn_mfma_f32_16x16x32_bf16(af[i][0], bfr[j][0], acc[i][j], 0, 0, 0);
        acc[i][j] = __builtin_amdgcn_mfma_f32_16x16x32_bf16(af[i][1], bfr[j][1], acc[i][j], 0, 0, 0);
      }
    __builtin_amdgcn_s_setprio(0);
    asm volatile("s_barrier" ::: "memory");
    if (kt + 2 < 16) STAGE(db, kt + 2);
  }

  const int mrow = m0 + wm * 64;
  const int ncol = n0 + wn * 64;
#pragma unroll
  for (int i = 0; i < 4; ++i)
#pragma unroll
    for (int j = 0; j < 4; ++j)
#pragma unroll
      for (int r = 0; r < 4; ++r) {
        int m = mrow + i * 16 + g * 4 + r;
        int n = ncol + j * 16 + lq;
        f_out[(size_t)m * CC + n] = acc[i][j][r] + bias[n];
      }
}

// ------- causal flash attention: 3-buffer K/V rotation, ONE barrier per tile -------
// Stage(t+2) issues at the TOP of tile t (target buffer freed by barrier t): lookahead
// 2 steps (~1600 cyc > HBM latency), second barrier eliminated (overwrite-guard is
// subsumed by the next tile's barrier — all t-1 LDS reads are lgkm-complete before
// any wave passes barrier t). LDS 66 KB -> 2 blocks/CU.
__global__ __launch_bounds__(256, 2) void attn_kernel(
    const u16* __restrict__ Q, const u16* __restrict__ K, const u16* __restrict__ Vt,
    const float* __restrict__ gm, const u32* __restrict__ fwords, u16* __restrict__ Y) {
  // LDS: K bufs 3x8192 @0 | V bufs 3x8192 @24576 | P 4 waves x 4608 @49152
  __shared__ __align__(16) char LDS[67584];
  const int flat = blockIdx.x;
  const int xcd = flat & 7, idx = flat >> 3;
  const int bh = xcd * 8 + (idx & 7);   // 8 heads per XCD
  const int jb = 15 - (idx >> 3);       // heavy-first (LPT backfill)
  const int b = bh >> 4, h = bh & 15;
  const int tid = threadIdx.x, lane = tid & 63, w = tid >> 6;
  const int lq = lane & 15, g = lane >> 4;
  const int qt = 4 * jb + w;
  const int q0 = qt * 32;
  const int nkt = (qt >> 1) + 1;
  const int nktm = 2 * jb + 2;
  const u32 fw = fwords[b];

  const u16* Qb = Q + (size_t)bh * TT * DD;
  const char* Kb = (const char*)(K + (size_t)bh * TT * DD);
  const char* Vb = (const char*)(Vt + (size_t)bh * DD * TT);

  const int l3 = lane >> 3, l7 = lane & 7;
  const int swb = (l7 * 16) ^ (l3 << 4);
  const char* kp0 = Kb + (2 * w + 0) * 1024 + l3 * 128 + swb;
  const char* kp1 = Kb + (2 * w + 1) * 1024 + l3 * 128 + swb;
  const char* vp0 = Vb + (size_t)((2 * w + 0) * 8 + l3) * 4096 + swb;
  const char* vp1 = Vb + (size_t)((2 * w + 1) * 8 + l3) * 4096 + swb;

  const int sw2 = (lq & 7) << 4;
  const int fb0 = lq * 128 + ((g * 16) ^ sw2);
  const int fb1 = lq * 128 + (((64) + g * 16) ^ sw2);
  const int pwb = 49152 + w * 4608 + lq * 144 + g * 8;
  const int prb = 49152 + w * 4608 + lq * 144 + g * 16;

  auto STAGE = [&](int buf, int kt2) {
    const int ko = kt2 * 8192, vo = kt2 * 128, lb = buf * 8192;
    __builtin_amdgcn_global_load_lds(
        (const __attribute__((address_space(1))) void*)(kp0 + ko),
        (__attribute__((address_space(3))) void*)(LDS + lb + (2 * w + 0) * 1024), 16, 0, 0);
    __builtin_amdgcn_global_load_lds(
        (const __attribute__((address_space(1))) void*)(kp1 + ko),
        (__attribute__((address_space(3))) void*)(LDS + lb + (2 * w + 1) * 1024), 16, 0, 0);
    __builtin_amdgcn_global_load_lds(
        (const __attribute__((address_space(1))) void*)(vp0 + vo),
        (__attribute__((address_space(3))) void*)(LDS + 24576 + lb + (2 * w + 0) * 1024), 16, 0, 0);
    __builtin_amdgcn_global_load_lds(
        (const __attribute__((address_space(1))) void*)(vp1 + vo),
        (__attribute__((address_space(3))) void*)(LDS + 24576 + lb + (2 * w + 1) * 1024), 16, 0, 0);
  };

  bf16x8 qf[2][2];
#pragma unroll
  for (int n = 0; n < 2; ++n)
#pragma unroll
    for (int ks = 0; ks < 2; ++ks)
      qf[n][ks] = *reinterpret_cast<const bf16x8*>(
          Qb + (size_t)(q0 + n * 16 + lq) * DD + ks * 32 + g * 8);

  const u16x8 onesu = {0x3F80, 0x3F80, 0x3F80, 0x3F80, 0x3F80, 0x3F80, 0x3F80, 0x3F80};
  const bf16x8 ones = __builtin_bit_cast(bf16x8, onesu);

  f32x4 o[4][2] = {};
  f32x4 l_acc[2] = {};
  float mrun[2] = {-1e30f, -1e30f};
  const f32x4 z4 = {0.f, 0.f, 0.f, 0.f};

  // prologue: stages 0,1 (lookahead 2 established by in-loop top-staging)
  STAGE(0, 0);
  STAGE(1, 1);

  int bcur = 0;  // buffer for tile kt; (kt+2)%3 == (bcur+2)%3 == (bcur-1)%3
  for (int kt = 0; kt < nktm; ++kt) {
    if (kt < nktm - 1)
      asm volatile("s_waitcnt vmcnt(4)" ::: "memory");
    else
      asm volatile("s_waitcnt vmcnt(0)" ::: "memory");
    asm volatile("s_barrier" ::: "memory");

    if (kt + 2 < nktm) {
      int b2 = bcur - 1; if (b2 < 0) b2 = 2;
      STAGE(b2, kt + 2);
    }

    if (kt < nkt) {
      const int kv0 = kt * 64;
      const char* kbuf = LDS + bcur * 8192;
      const char* vbuf = LDS + 24576 + bcur * 8192;
      bf16x8 kf0[4], kf1[4];
#pragma unroll
      for (int m = 0; m < 4; ++m) {
        kf0[m] = *reinterpret_cast<const bf16x8*>(kbuf + m * 2048 + fb0);
        kf1[m] = *reinterpret_cast<const bf16x8*>(kbuf + m * 2048 + fb1);
      }
      f32x4 s[4][2];
      __builtin_amdgcn_s_setprio(1);
#pragma unroll
      for (int m = 0; m < 4; ++m)
#pragma unroll
        for (int n = 0; n < 2; ++n) {
          s[m][n] = __builtin_amdgcn_mfma_f32_16x16x32_bf16(kf0[m], qf[n][0], z4, 0, 0, 0);
          s[m][n] = __builtin_amdgcn_mfma_f32_16x16x32_bf16(kf1[m], qf[n][1], s[m][n], 0, 0, 0);
        }
      __builtin_amdgcn_s_setprio(0);

      if (!((fw >> kt) & 1u)) {
#pragma unroll
        for (int m = 0; m < 4; ++m) {
          float4 mv = *reinterpret_cast<const float4*>(gm + b * TT + kv0 + m * 16 + g * 4);
#pragma unroll
          for (int n = 0; n < 2; ++n) {
            s[m][n][0] += mv.x; s[m][n][1] += mv.y;
            s[m][n][2] += mv.z; s[m][n][3] += mv.w;
          }
        }
      }
      if (kt == nkt - 1) {
#pragma unroll
        for (int n = 0; n < 2; ++n) {
          const int q = q0 + n * 16 + lq;
#pragma unroll
          for (int m = 0; m < 4; ++m)
#pragma unroll
            for (int r = 0; r < 4; ++r) {
              int kv = kv0 + m * 16 + g * 4 + r;
              s[m][n][r] = (kv <= q) ? s[m][n][r] : -1e30f;
            }
        }
      }

#pragma unroll
      for (int n = 0; n < 2; ++n) {
        float m1 = max3f(s[0][n][0], s[0][n][1], s[0][n][2]);
        float m2 = max3f(s[0][n][3], s[1][n][0], s[1][n][1]);
        float m3 = max3f(s[1][n][2], s[1][n][3], s[2][n][0]);
        float m4 = max3f(s[2][n][1], s[2][n][2], s[2][n][3]);
        float m5 = max3f(s[3][n][0], s[3][n][1], s[3][n][2]);
        float rm = fmaxf(max3f(m1, m2, m3), max3f(m4, m5, s[3][n][3]));
        if (!__all(rm <= mrun[n] + 8.f)) {
          float rg = fmaxf(rm, __shfl_xor(rm, 16));
          rg = fmaxf(rg, __shfl_xor(rg, 32));
          float mnew = fmaxf(mrun[n], rg);
          float corr = __builtin_exp2f(mrun[n] - mnew);
          mrun[n] = mnew;
          l_acc[n] *= corr;
#pragma unroll
          for (int nd = 0; nd < 4; ++nd)
#pragma unroll
            for (int r = 0; r < 4; ++r) o[nd][n][r] *= corr;
        }
        const float mn = mrun[n];
#pragma unroll
        for (int m = 0; m < 4; ++m) {
          float p0 = __builtin_exp2f(s[m][n][0] - mn);
          float p1 = __builtin_exp2f(s[m][n][1] - mn);
          float p2 = __builtin_exp2f(s[m][n][2] - mn);
          float p3 = __builtin_exp2f(s[m][n][3] - mn);
          u32 wa, wb;
          asm("v_cvt_pk_bf16_f32 %0, %1, %2" : "=v"(wa) : "v"(p0), "v"(p1));
          asm("v_cvt_pk_bf16_f32 %0, %1, %2" : "=v"(wb) : "v"(p2), "v"(p3));
          uint2 pw; pw.x = wa; pw.y = wb;
          *reinterpret_cast<uint2*>(LDS + pwb + n * 2304 + m * 32) = pw;
        }
      }

      asm volatile("s_waitcnt lgkmcnt(0)" ::: "memory");  // P visible to own wave
      __builtin_amdgcn_sched_barrier(0);                  // rule #18

      __builtin_amdgcn_s_setprio(1);
#pragma unroll
      for (int ks = 0; ks < 2; ++ks) {
        const int fb = ks ? fb1 : fb0;
        bf16x8 pf0 = *reinterpret_cast<const bf16x8*>(LDS + prb + 0 * 2304 + ks * 64);
        bf16x8 pf1 = *reinterpret_cast<const bf16x8*>(LDS + prb + 1 * 2304 + ks * 64);
#pragma unroll
        for (int nd = 0; nd < 4; ++nd) {
          bf16x8 vf = *reinterpret_cast<const bf16x8*>(vbuf + nd * 2048 + fb);
          o[nd][0] = __builtin_amdgcn_mfma_f32_16x16x32_bf16(vf, pf0, o[nd][0], 0, 0, 0);
          o[nd][1] = __builtin_amdgcn_mfma_f32_16x16x32_bf16(vf, pf1, o[nd][1], 0, 0, 0);
        }
        l_acc[0] = __builtin_amdgcn_mfma_f32_16x16x32_bf16(ones, pf0, l_acc[0], 0, 0, 0);
        l_acc[1] = __builtin_amdgcn_mfma_f32_16x16x32_bf16(ones, pf1, l_acc[1], 0, 0, 0);
      }
      __builtin_amdgcn_s_setprio(0);
    }

    bcur = (bcur == 2) ? 0 : bcur + 1;
  }

  // epilogue: l complete per lane (ones-MFMA) -> no cross-lane reduce
#pragma unroll
  for (int n = 0; n < 2; ++n) {
    float inv = 1.0f / l_acc[n][0];
    const int q = q0 + n * 16 + lq;
#pragma unroll
    for (int nd = 0; nd < 4; ++nd) {
      u16x4 yv;
#pragma unroll
      for (int r = 0; r < 4; ++r) yv[r] = bfc(o[nd][n][r] * inv);
      *reinterpret_cast<u16x4*>(
          Y + ((size_t)(b * TT + q)) * CC + h * DD + nd * 16 + g * 4) = yv;
    }
  }
}

extern "C" void kernel_launch(void* const* d_in, const int* in_sizes, int n_in,
                              void* d_out, int out_size, void* d_ws, size_t ws_size,
                              hipStream_t stream) {
  const float* x  = (const float*)d_in[0];
  const int*   am = (const int*)d_in[1];
  const float* Wq = (const float*)d_in[2];
  const float* bq = (const float*)d_in[3];
  const float* Wk = (const float*)d_in[4];
  const float* bk = (const float*)d_in[5];
  const float* Wv = (const float*)d_in[6];
  const float* bv = (const float*)d_in[7];
  const float* Wp = (const float*)d_in[8];
  const float* bp = (const float*)d_in[9];
  float* out = (float*)d_out;

  char* ws = (char*)d_ws;
  u16* xb    = (u16*)(ws);                        // 16 MB  [8192][1024] bf16
  u16* wqkvT = (u16*)(ws + (16ull << 20));        //  6 MB  [3072][1024] bf16 (W^T)
  u16* wpT   = (u16*)(ws + (22ull << 20));        //  2 MB  [1024][1024] bf16 (Wp^T)
  u16* qw    = (u16*)(ws + (24ull << 20));        // 16 MB  [B,H,T,D] bf16 (pre-scaled)
  u16* kw    = (u16*)(ws + (40ull << 20));        // 16 MB  [B,H,T,D] bf16
  u16* vw    = (u16*)(ws + (56ull << 20));        // 16 MB  [B,H,D,T] bf16 (transposed!)
  u16* yb    = (u16*)(ws + (72ull << 20));        // 16 MB  [B,T,C] bf16
  float* gm  = (float*)d_out;                     // 32 KB [B][T] additive mask (dead until proj)
  u32* fwords = (u32*)((char*)d_out + (64ull << 10));  // [B] chunk-valid bitmask

  prep_kernel<<<dim3(8196), 256, 0, stream>>>(
      x, am, Wq, Wk, Wv, Wp, xb, wqkvT, wpT, gm, fwords);
  qkv_gemm_kernel<<<dim3(64, 24), 256, 0, stream>>>(
      xb, wqkvT, bq, bk, bv, qw, kw, vw);
  attn_kernel<<<dim3(1024), 256, 0, stream>>>(qw, kw, vw, gm, fwords, yb);
  proj_gemm_kernel<<<dim3(64, 8), 256, 0, stream>>>(yb, wpT, bp, out);
}

// Round 15
// 157.398 us; speedup vs baseline: 1.1674x; 1.1674x over previous
//
#include <hip/hip_runtime.h>

#define BB 4
#define TT 2048
#define CC 1024
#define HH 16
#define DD 64

typedef unsigned short u16;
typedef unsigned int u32;
typedef __bf16 bf16;
typedef __attribute__((ext_vector_type(8))) bf16 bf16x8;
typedef __attribute__((ext_vector_type(8))) u16 u16x8;
typedef __attribute__((ext_vector_type(4))) u16 u16x4;
typedef __attribute__((ext_vector_type(4))) float f32x4;

static __device__ __forceinline__ u16 f2b(float f) {
  unsigned u = __builtin_bit_cast(unsigned, f);
  u += 0x7fffu + ((u >> 16) & 1u);
  return (u16)(u >> 16);
}
static __device__ __forceinline__ u16 bfc(float f) {
  return __builtin_bit_cast(u16, (__bf16)f);
}
static __device__ __forceinline__ float max3f(float a, float b, float c) {
  float d;
  asm("v_max3_f32 %0, %1, %2, %3" : "=v"(d) : "v"(a), "v"(b), "v"(c));
  return d;
}

// ---- fused prep: [0,4096) cvt x->bf16 | [4096,8192) transpose W | [8192,8196) mask ----
__global__ __launch_bounds__(256) void prep_kernel(
    const float* __restrict__ x, const int* __restrict__ am,
    const float* __restrict__ w0, const float* __restrict__ w1,
    const float* __restrict__ w2, const float* __restrict__ w3,
    u16* __restrict__ xb, u16* __restrict__ wqkvT, u16* __restrict__ wpT,
    float* __restrict__ gm, u32* __restrict__ fwords) {
  __shared__ float t[32][33];
  const int bid = blockIdx.x, tid = threadIdx.x;
  if (bid < 4096) {
    int i = bid * 256 + tid;
    const float4* p4 = reinterpret_cast<const float4*>(x) + (size_t)i * 2;
    float4 a = p4[0], b = p4[1];
    u16x8 o;
    o[0] = f2b(a.x); o[1] = f2b(a.y); o[2] = f2b(a.z); o[3] = f2b(a.w);
    o[4] = f2b(b.x); o[5] = f2b(b.y); o[6] = f2b(b.z); o[7] = f2b(b.w);
    *reinterpret_cast<u16x8*>(xb + (size_t)i * 8) = o;
  } else if (bid < 8192) {
    int r2 = bid - 4096;
    int z = r2 >> 10, rem = r2 & 1023;
    int k0 = (rem & 31) * 32, n0 = (rem >> 5) * 32;
    const float* src = z == 0 ? w0 : z == 1 ? w1 : z == 2 ? w2 : w3;
    u16* dst = z < 3 ? wqkvT + (size_t)z * CC * CC : wpT;
    int tx = tid & 31, ty = tid >> 5;
#pragma unroll
    for (int i = 0; i < 4; ++i)
      t[ty + i * 8][tx] = src[(size_t)(k0 + ty + i * 8) * CC + n0 + tx];
    __syncthreads();
#pragma unroll
    for (int i = 0; i < 4; ++i)
      dst[(size_t)(n0 + ty + i * 8) * CC + k0 + tx] = f2b(t[tx][ty + i * 8]);
  } else {
    __shared__ u32 sf[32];
    int b = bid - 8192;
    int lane = tid & 63, w = tid >> 6;
#pragma unroll
    for (int j = 0; j < 8; ++j) {
      int c = w * 8 + j;
      int i = c * 64 + lane;
      int v = am[b * TT + i];
      gm[b * TT + i] = v ? 0.f : -1e30f;
      unsigned long long bal = __ballot(v != 0);
      if (lane == 0) sf[c] = (bal == ~0ull) ? 1u : 0u;
    }
    __syncthreads();
    if (tid == 0) {
      u32 fw = 0;
      for (int c = 0; c < 32; ++c) fw |= sf[c] << c;
      fwords[b] = fw;
    }
  }
}

// ------- QKV GEMM: 128x128, BK=64, dbuf swizzled LDS + counted vmcnt (validated r12/r13) -------
// NO XCD swizzle: linear dispatch is already L2/L3-optimal here (r14: swizzle = 5x FETCH).
__global__ __launch_bounds__(256) void qkv_gemm_kernel(
    const u16* __restrict__ A, const u16* __restrict__ Bt,
    const float* __restrict__ bq, const float* __restrict__ bk, const float* __restrict__ bv,
    u16* __restrict__ q_out, u16* __restrict__ k_out, u16* __restrict__ v_out) {
  __shared__ __align__(16) char LDS[65536];  // A[2][128*64] | B[2][128*64] bf16
  const int tid = threadIdx.x, lane = tid & 63, w = tid >> 6;
  const int wm = w >> 1, wn = w & 1;
  const int lq = lane & 15, g = lane >> 4;
  const int m0 = blockIdx.x * 128, n0 = blockIdx.y * 128;
  const int l3 = lane >> 3;
  const int swb = ((lane & 7) ^ (l3 & 7)) * 16;
  f32x4 acc[4][4] = {};

  auto STAGE = [&](int db, int kt) {
    const int ko = kt * 128;
#pragma unroll
    for (int r = 0; r < 4; ++r) {
      int rb = r * 32 + w * 8;
      __builtin_amdgcn_global_load_lds(
          (const __attribute__((address_space(1))) void*)(
              (const char*)A + (size_t)(m0 + rb + l3) * 2048 + ko + swb),
          (__attribute__((address_space(3))) void*)(LDS + db * 16384 + rb * 128), 16, 0, 0);
      __builtin_amdgcn_global_load_lds(
          (const __attribute__((address_space(1))) void*)(
              (const char*)Bt + (size_t)(n0 + rb + l3) * 2048 + ko + swb),
          (__attribute__((address_space(3))) void*)(LDS + 32768 + db * 16384 + rb * 128), 16, 0, 0);
    }
  };

  const int acol0 = (g * 16) ^ ((lq & 7) << 4);
  const int acol1 = (64 + g * 16) ^ ((lq & 7) << 4);
  const int aBase = wm * 8192 + lq * 128;
  const int bBase = 32768 + wn * 8192 + lq * 128;

  STAGE(0, 0);
  STAGE(1, 1);
  for (int kt = 0; kt < 16; ++kt) {
    if (kt == 15) asm volatile("s_waitcnt vmcnt(0)" ::: "memory");
    else          asm volatile("s_waitcnt vmcnt(8)" ::: "memory");
    asm volatile("s_barrier" ::: "memory");
    const int db = kt & 1;
    const char* la = LDS + db * 16384 + aBase;
    const char* lb = LDS + db * 16384 + bBase;
    bf16x8 af[4][2], bfr[4][2];
#pragma unroll
    for (int i = 0; i < 4; ++i) {
      af[i][0] = *reinterpret_cast<const bf16x8*>(la + i * 2048 + acol0);
      af[i][1] = *reinterpret_cast<const bf16x8*>(la + i * 2048 + acol1);
      bfr[i][0] = *reinterpret_cast<const bf16x8*>(lb + i * 2048 + acol0);
      bfr[i][1] = *reinterpret_cast<const bf16x8*>(lb + i * 2048 + acol1);
    }
    asm volatile("s_waitcnt lgkmcnt(0)" ::: "memory");
    __builtin_amdgcn_sched_barrier(0);
    __builtin_amdgcn_s_setprio(1);
#pragma unroll
    for (int i = 0; i < 4; ++i)
#pragma unroll
      for (int j = 0; j < 4; ++j) {
        acc[i][j] = __builtin_amdgcn_mfma_f32_16x16x32_bf16(af[i][0], bfr[j][0], acc[i][j], 0, 0, 0);
        acc[i][j] = __builtin_amdgcn_mfma_f32_16x16x32_bf16(af[i][1], bfr[j][1], acc[i][j], 0, 0, 0);
      }
    __builtin_amdgcn_s_setprio(0);
    asm volatile("s_barrier" ::: "memory");
    if (kt + 2 < 16) STAGE(db, kt + 2);
  }

  // epilogue: scatter
  const int g3 = n0 >> 10;  // 0:Q 1:K 2:V (uniform per block; 1024 % 128 == 0)
  const int mrow = m0 + wm * 64;
  const int ncol = n0 + wn * 64;
  if (g3 < 2) {
    u16* dst = g3 == 0 ? q_out : k_out;
    const float* bias = g3 == 0 ? bq : bk;
    const float scl = g3 == 0 ? 0.18033688f : 1.0f;  // Q pre-scale: 0.125*log2(e)
#pragma unroll
    for (int i = 0; i < 4; ++i)
#pragma unroll
      for (int j = 0; j < 4; ++j) {
        int n = ncol + j * 16 + lq;
        int h = (n >> 6) & 15, d = n & 63;
        float bb = bias[n & 1023];
#pragma unroll
        for (int r = 0; r < 4; ++r) {
          int m = mrow + i * 16 + g * 4 + r;
          int b = m >> 11, t = m & 2047;
          dst[(((size_t)(b * HH + h)) * TT + t) * DD + d] = f2b((acc[i][j][r] + bb) * scl);
        }
      }
  } else {
#pragma unroll
    for (int i = 0; i < 4; ++i)
#pragma unroll
      for (int j = 0; j < 4; ++j) {
        int n = ncol + j * 16 + lq;
        int h = (n >> 6) & 15, d = n & 63;
        float bb = bv[n & 1023];
        int mb = mrow + i * 16 + g * 4;
        int b = mb >> 11, t = mb & 2047;
        u16x4 vv;
#pragma unroll
        for (int r = 0; r < 4; ++r) vv[r] = f2b(acc[i][j][r] + bb);
        *reinterpret_cast<u16x4*>(v_out + (((size_t)(b * HH + h)) * DD + d) * TT + t) = vv;
      }
  }
}

// -------- proj GEMM: 128x128, BK=64, dbuf swizzled LDS + counted vmcnt (validated) --------
__global__ __launch_bounds__(256) void proj_gemm_kernel(
    const u16* __restrict__ A, const u16* __restrict__ Bt,
    const float* __restrict__ bias, float* __restrict__ f_out) {
  __shared__ __align__(16) char LDS[65536];
  const int tid = threadIdx.x, lane = tid & 63, w = tid >> 6;
  const int wm = w >> 1, wn = w & 1;
  const int lq = lane & 15, g = lane >> 4;
  const int m0 = blockIdx.x * 128, n0 = blockIdx.y * 128;
  const int l3 = lane >> 3;
  const int swb = ((lane & 7) ^ (l3 & 7)) * 16;
  f32x4 acc[4][4] = {};

  auto STAGE = [&](int db, int kt) {
    const int ko = kt * 128;
#pragma unroll
    for (int r = 0; r < 4; ++r) {
      int rb = r * 32 + w * 8;
      __builtin_amdgcn_global_load_lds(
          (const __attribute__((address_space(1))) void*)(
              (const char*)A + (size_t)(m0 + rb + l3) * 2048 + ko + swb),
          (__attribute__((address_space(3))) void*)(LDS + db * 16384 + rb * 128), 16, 0, 0);
      __builtin_amdgcn_global_load_lds(
          (const __attribute__((address_space(1))) void*)(
              (const char*)Bt + (size_t)(n0 + rb + l3) * 2048 + ko + swb),
          (__attribute__((address_space(3))) void*)(LDS + 32768 + db * 16384 + rb * 128), 16, 0, 0);
    }
  };

  const int acol0 = (g * 16) ^ ((lq & 7) << 4);
  const int acol1 = (64 + g * 16) ^ ((lq & 7) << 4);
  const int aBase = wm * 8192 + lq * 128;
  const int bBase = 32768 + wn * 8192 + lq * 128;

  STAGE(0, 0);
  STAGE(1, 1);
  for (int kt = 0; kt < 16; ++kt) {
    if (kt == 15) asm volatile("s_waitcnt vmcnt(0)" ::: "memory");
    else          asm volatile("s_waitcnt vmcnt(8)" ::: "memory");
    asm volatile("s_barrier" ::: "memory");
    const int db = kt & 1;
    const char* la = LDS + db * 16384 + aBase;
    const char* lb = LDS + db * 16384 + bBase;
    bf16x8 af[4][2], bfr[4][2];
#pragma unroll
    for (int i = 0; i < 4; ++i) {
      af[i][0] = *reinterpret_cast<const bf16x8*>(la + i * 2048 + acol0);
      af[i][1] = *reinterpret_cast<const bf16x8*>(la + i * 2048 + acol1);
      bfr[i][0] = *reinterpret_cast<const bf16x8*>(lb + i * 2048 + acol0);
      bfr[i][1] = *reinterpret_cast<const bf16x8*>(lb + i * 2048 + acol1);
    }
    asm volatile("s_waitcnt lgkmcnt(0)" ::: "memory");
    __builtin_amdgcn_sched_barrier(0);
    __builtin_amdgcn_s_setprio(1);
#pragma unroll
    for (int i = 0; i < 4; ++i)
#pragma unroll
      for (int j = 0; j < 4; ++j) {
        acc[i][j] = __builtin_amdgcn_mfma_f32_16x16x32_bf16(af[i][0], bfr[j][0], acc[i][j], 0, 0, 0);
        acc[i][j] = __builtin_amdgcn_mfma_f32_16x16x32_bf16(af[i][1], bfr[j][1], acc[i][j], 0, 0, 0);
      }
    __builtin_amdgcn_s_setprio(0);
    asm volatile("s_barrier" ::: "memory");
    if (kt + 2 < 16) STAGE(db, kt + 2);
  }

  const int mrow = m0 + wm * 64;
  const int ncol = n0 + wn * 64;
#pragma unroll
  for (int i = 0; i < 4; ++i)
#pragma unroll
    for (int j = 0; j < 4; ++j)
#pragma unroll
      for (int r = 0; r < 4; ++r) {
        int m = mrow + i * 16 + g * 4 + r;
        int n = ncol + j * 16 + lq;
        f_out[(size_t)m * CC + n] = acc[i][j][r] + bias[n];
      }
}

// ------- causal flash attention: 4-wave blocks, LDS-staged K/V dbuf + counted vmcnt -------
// (exact r11/r13 kernel — validated 70 us; 1024 blocks, 3 resident/CU, LPT backfill;
// ones-MFMA row-sum; max3 tree; gated defer-rescale; log2-domain via pre-scaled Q.)
__global__ __launch_bounds__(256, 2) void attn_kernel(
    const u16* __restrict__ Q, const u16* __restrict__ K, const u16* __restrict__ Vt,
    const float* __restrict__ gm, const u32* __restrict__ fwords, u16* __restrict__ Y) {
  __shared__ __align__(16) char LDS[51200];
  const int flat = blockIdx.x;
  const int xcd = flat & 7, idx = flat >> 3;
  const int bh = xcd * 8 + (idx & 7);
  const int jb = 15 - (idx >> 3);
  const int b = bh >> 4, h = bh & 15;
  const int tid = threadIdx.x, lane = tid & 63, w = tid >> 6;
  const int lq = lane & 15, g = lane >> 4;
  const int qt = 4 * jb + w;
  const int q0 = qt * 32;
  const int nkt = (qt >> 1) + 1;
  const int nktm = 2 * jb + 2;
  const u32 fw = fwords[b];

  const u16* Qb = Q + (size_t)bh * TT * DD;
  const char* Kb = (const char*)(K + (size_t)bh * TT * DD);
  const char* Vb = (const char*)(Vt + (size_t)bh * DD * TT);

  const int l3 = lane >> 3, l7 = lane & 7;
  const int swb = (l7 * 16) ^ (l3 << 4);
  const char* kp0 = Kb + (2 * w + 0) * 1024 + l3 * 128 + swb;
  const char* kp1 = Kb + (2 * w + 1) * 1024 + l3 * 128 + swb;
  const char* vp0 = Vb + (size_t)((2 * w + 0) * 8 + l3) * 4096 + swb;
  const char* vp1 = Vb + (size_t)((2 * w + 1) * 8 + l3) * 4096 + swb;

  const int sw2 = (lq & 7) << 4;
  const int fb0 = lq * 128 + ((g * 16) ^ sw2);
  const int fb1 = lq * 128 + (((64) + g * 16) ^ sw2);
  const int pwb = 32768 + w * 4608 + lq * 144 + g * 8;
  const int prb = 32768 + w * 4608 + lq * 144 + g * 16;

  auto STAGE = [&](int buf, int kt2) {
    const int ko = kt2 * 8192, vo = kt2 * 128, lb = buf * 8192;
    __builtin_amdgcn_global_load_lds(
        (const __attribute__((address_space(1))) void*)(kp0 + ko),
        (__attribute__((address_space(3))) void*)(LDS + lb + (2 * w + 0) * 1024), 16, 0, 0);
    __builtin_amdgcn_global_load_lds(
        (const __attribute__((address_space(1))) void*)(kp1 + ko),
        (__attribute__((address_space(3))) void*)(LDS + lb + (2 * w + 1) * 1024), 16, 0, 0);
    __builtin_amdgcn_global_load_lds(
        (const __attribute__((address_space(1))) void*)(vp0 + vo),
        (__attribute__((address_space(3))) void*)(LDS + 16384 + lb + (2 * w + 0) * 1024), 16, 0, 0);
    __builtin_amdgcn_global_load_lds(
        (const __attribute__((address_space(1))) void*)(vp1 + vo),
        (__attribute__((address_space(3))) void*)(LDS + 16384 + lb + (2 * w + 1) * 1024), 16, 0, 0);
  };

  bf16x8 qf[2][2];
#pragma unroll
  for (int n = 0; n < 2; ++n)
#pragma unroll
    for (int ks = 0; ks < 2; ++ks)
      qf[n][ks] = *reinterpret_cast<const bf16x8*>(
          Qb + (size_t)(q0 + n * 16 + lq) * DD + ks * 32 + g * 8);

  const u16x8 onesu = {0x3F80, 0x3F80, 0x3F80, 0x3F80, 0x3F80, 0x3F80, 0x3F80, 0x3F80};
  const bf16x8 ones = __builtin_bit_cast(bf16x8, onesu);

  f32x4 o[4][2] = {};
  f32x4 l_acc[2] = {};
  float mrun[2] = {-1e30f, -1e30f};
  const f32x4 z4 = {0.f, 0.f, 0.f, 0.f};

  STAGE(0, 0);
  STAGE(1, 1);

  auto TILE = [&](int BUF, int kt) {
    if (kt < nktm - 1)
      asm volatile("s_waitcnt vmcnt(4)" ::: "memory");
    else
      asm volatile("s_waitcnt vmcnt(0)" ::: "memory");
    asm volatile("s_barrier" ::: "memory");

    if (kt < nkt) {
      const int kv0 = kt * 64;
      bf16x8 kf0[4], kf1[4];
#pragma unroll
      for (int m = 0; m < 4; ++m) {
        kf0[m] = *reinterpret_cast<const bf16x8*>(LDS + BUF * 8192 + m * 2048 + fb0);
        kf1[m] = *reinterpret_cast<const bf16x8*>(LDS + BUF * 8192 + m * 2048 + fb1);
      }
      f32x4 s[4][2];
      __builtin_amdgcn_s_setprio(1);
#pragma unroll
      for (int m = 0; m < 4; ++m)
#pragma unroll
        for (int n = 0; n < 2; ++n) {
          s[m][n] = __builtin_amdgcn_mfma_f32_16x16x32_bf16(kf0[m], qf[n][0], z4, 0, 0, 0);
          s[m][n] = __builtin_amdgcn_mfma_f32_16x16x32_bf16(kf1[m], qf[n][1], s[m][n], 0, 0, 0);
        }
      __builtin_amdgcn_s_setprio(0);

      if (!((fw >> kt) & 1u)) {
#pragma unroll
        for (int m = 0; m < 4; ++m) {
          float4 mv = *reinterpret_cast<const float4*>(gm + b * TT + kv0 + m * 16 + g * 4);
#pragma unroll
          for (int n = 0; n < 2; ++n) {
            s[m][n][0] += mv.x; s[m][n][1] += mv.y;
            s[m][n][2] += mv.z; s[m][n][3] += mv.w;
          }
        }
      }
      if (kt == nkt - 1) {
#pragma unroll
        for (int n = 0; n < 2; ++n) {
          const int q = q0 + n * 16 + lq;
#pragma unroll
          for (int m = 0; m < 4; ++m)
#pragma unroll
            for (int r = 0; r < 4; ++r) {
              int kv = kv0 + m * 16 + g * 4 + r;
              s[m][n][r] = (kv <= q) ? s[m][n][r] : -1e30f;
            }
        }
      }

#pragma unroll
      for (int n = 0; n < 2; ++n) {
        float m1 = max3f(s[0][n][0], s[0][n][1], s[0][n][2]);
        float m2 = max3f(s[0][n][3], s[1][n][0], s[1][n][1]);
        float m3 = max3f(s[1][n][2], s[1][n][3], s[2][n][0]);
        float m4 = max3f(s[2][n][1], s[2][n][2], s[2][n][3]);
        float m5 = max3f(s[3][n][0], s[3][n][1], s[3][n][2]);
        float rm = fmaxf(max3f(m1, m2, m3), max3f(m4, m5, s[3][n][3]));
        if (!__all(rm <= mrun[n] + 8.f)) {
          float rg = fmaxf(rm, __shfl_xor(rm, 16));
          rg = fmaxf(rg, __shfl_xor(rg, 32));
          float mnew = fmaxf(mrun[n], rg);
          float corr = __builtin_exp2f(mrun[n] - mnew);
          mrun[n] = mnew;
          l_acc[n] *= corr;
#pragma unroll
          for (int nd = 0; nd < 4; ++nd)
#pragma unroll
            for (int r = 0; r < 4; ++r) o[nd][n][r] *= corr;
        }
        const float mn = mrun[n];
#pragma unroll
        for (int m = 0; m < 4; ++m) {
          float p0 = __builtin_exp2f(s[m][n][0] - mn);
          float p1 = __builtin_exp2f(s[m][n][1] - mn);
          float p2 = __builtin_exp2f(s[m][n][2] - mn);
          float p3 = __builtin_exp2f(s[m][n][3] - mn);
          u32 wa, wb;
          asm("v_cvt_pk_bf16_f32 %0, %1, %2" : "=v"(wa) : "v"(p0), "v"(p1));
          asm("v_cvt_pk_bf16_f32 %0, %1, %2" : "=v"(wb) : "v"(p2), "v"(p3));
          uint2 pw; pw.x = wa; pw.y = wb;
          *reinterpret_cast<uint2*>(LDS + pwb + n * 2304 + m * 32) = pw;
        }
      }

      asm volatile("s_waitcnt lgkmcnt(0)" ::: "memory");
      __builtin_amdgcn_sched_barrier(0);

      __builtin_amdgcn_s_setprio(1);
#pragma unroll
      for (int ks = 0; ks < 2; ++ks) {
        const int fb = ks ? fb1 : fb0;
        bf16x8 pf0 = *reinterpret_cast<const bf16x8*>(LDS + prb + 0 * 2304 + ks * 64);
        bf16x8 pf1 = *reinterpret_cast<const bf16x8*>(LDS + prb + 1 * 2304 + ks * 64);
#pragma unroll
        for (int nd = 0; nd < 4; ++nd) {
          bf16x8 vf = *reinterpret_cast<const bf16x8*>(LDS + 16384 + BUF * 8192 + nd * 2048 + fb);
          o[nd][0] = __builtin_amdgcn_mfma_f32_16x16x32_bf16(vf, pf0, o[nd][0], 0, 0, 0);
          o[nd][1] = __builtin_amdgcn_mfma_f32_16x16x32_bf16(vf, pf1, o[nd][1], 0, 0, 0);
        }
        l_acc[0] = __builtin_amdgcn_mfma_f32_16x16x32_bf16(ones, pf0, l_acc[0], 0, 0, 0);
        l_acc[1] = __builtin_amdgcn_mfma_f32_16x16x32_bf16(ones, pf1, l_acc[1], 0, 0, 0);
      }
      __builtin_amdgcn_s_setprio(0);
    }

    asm volatile("s_barrier" ::: "memory");
    if (kt + 2 < nktm) STAGE(BUF, kt + 2);
  };

  for (int kt = 0; kt < nktm; kt += 2) {
    TILE(0, kt);
    TILE(1, kt + 1);
  }

#pragma unroll
  for (int n = 0; n < 2; ++n) {
    float inv = 1.0f / l_acc[n][0];
    const int q = q0 + n * 16 + lq;
#pragma unroll
    for (int nd = 0; nd < 4; ++nd) {
      u16x4 yv;
#pragma unroll
      for (int r = 0; r < 4; ++r) yv[r] = bfc(o[nd][n][r] * inv);
      *reinterpret_cast<u16x4*>(
          Y + ((size_t)(b * TT + q)) * CC + h * DD + nd * 16 + g * 4) = yv;
    }
  }
}

extern "C" void kernel_launch(void* const* d_in, const int* in_sizes, int n_in,
                              void* d_out, int out_size, void* d_ws, size_t ws_size,
                              hipStream_t stream) {
  const float* x  = (const float*)d_in[0];
  const int*   am = (const int*)d_in[1];
  const float* Wq = (const float*)d_in[2];
  const float* bq = (const float*)d_in[3];
  const float* Wk = (const float*)d_in[4];
  const float* bk = (const float*)d_in[5];
  const float* Wv = (const float*)d_in[6];
  const float* bv = (const float*)d_in[7];
  const float* Wp = (const float*)d_in[8];
  const float* bp = (const float*)d_in[9];
  float* out = (float*)d_out;

  char* ws = (char*)d_ws;
  u16* xb    = (u16*)(ws);                        // 16 MB  [8192][1024] bf16
  u16* wqkvT = (u16*)(ws + (16ull << 20));        //  6 MB  [3072][1024] bf16 (W^T)
  u16* wpT   = (u16*)(ws + (22ull << 20));        //  2 MB  [1024][1024] bf16 (Wp^T)
  u16* qw    = (u16*)(ws + (24ull << 20));        // 16 MB  [B,H,T,D] bf16 (pre-scaled)
  u16* kw    = (u16*)(ws + (40ull << 20));        // 16 MB  [B,H,T,D] bf16
  u16* vw    = (u16*)(ws + (56ull << 20));        // 16 MB  [B,H,D,T] bf16 (transposed!)
  u16* yb    = (u16*)(ws + (72ull << 20));        // 16 MB  [B,T,C] bf16
  float* gm  = (float*)d_out;                     // 32 KB [B][T] additive mask (dead until proj)
  u32* fwords = (u32*)((char*)d_out + (64ull << 10));  // [B] chunk-valid bitmask

  prep_kernel<<<dim3(8196), 256, 0, stream>>>(
      x, am, Wq, Wk, Wv, Wp, xb, wqkvT, wpT, gm, fwords);
  qkv_gemm_kernel<<<dim3(64, 24), 256, 0, stream>>>(
      xb, wqkvT, bq, bk, bv, qw, kw, vw);
  attn_kernel<<<dim3(1024), 256, 0, stream>>>(qw, kw, vw, gm, fwords, yb);
  proj_gemm_kernel<<<dim3(64, 8), 256, 0, stream>>>(yb, wpT, bp, out);
}